// Round 14
// baseline (1618.934 us; speedup 1.0000x reference)
//
#include <hip/hip_runtime.h>
#include <hip/hip_bf16.h>

// MPNN: N=100000 nodes, E=1600000 edges, D=128, L=4, G=64.
// All GEMM-shaped work on MFMA bf16 (fp32 accumulate), fp32 residual stream h.
//   prep: fold BN into W2 (both MLPs), transpose all B-matrices to [n][k] bf16,
//         counting-sort edges by dst, per-64-edge-tile segment-start bitmasks.
//   per layer:
//     edge_kernel (1 tile/block, 4 barriers, XCD-swizzled, packed-f32 VALU,
//         Q-only register prefetch, b1 pre-folded into P, ~19KB LDS, (256,5)):
//         t = relu(P'[dst]+Q[src]+ea@W1c) -> bf16 LDS (Tl)   [P' = h@W1a + b1]
//         m = relu(t@W2f+b2f)   (MFMA, W2 from L2) -> written back into Tl
//         mask-driven segmented reduce -> aggr (256-B-contiguous store groups)
//     upd_kernel (32-row tiles, ~17KB LDS, (256,6)):
//                  u1 = relu([h|aggr]@U1+ub1) (MFMA K=256) -> bf16 LDS overlay
//                  h += relu(u1@U2f+uB2f)     (MFMA K=128), in-place
//                  + fused next-layer P'/Q = h_new @ W1ab (+b1_next on P)
//                  + fused aggr re-zero for the next layer (replaces memsets)
//     pq_kernel additionally zeroes layer-0 aggr (last memset fused away).
// XCD swizzle: default dispatch round-robins blocks over 8 XCDs; remap
// b -> (b&7)*per + (b>>3) so each XCD owns a contiguous edge range -> its
// P-gather slice (~3.2MB) fits the 4MB per-XCD L2; aggr writes XCD-local.
// Ledger:
//  R1: persistent blocks + per-XCD atomic counters tripled hbm_bytes ->
//      static blocks. Packed f32x2 VALU verified -> kept.
//  R3: VALU cuts alone don't move latency-bound edge; 256-B store groups.
//  R4/R8: launch_bounds below unified (arch+acc) demand SPILLS (hbm 3-6x).
//  R5/R7: Q-only prefetch + 1-tile blocks + (256,5): edge 239, occ 46.5.
//  R9: edge at 6 waves/SIMD thrashes per-XCD L2 (hbm 0.35->0.62) ->
//      edge occupancy optimum is 5 waves/SIMD. Edge is FROZEN since R10.
//  R10: b1-fold into P: edge 234.5. R11: upd/pq bounds neutral.
//  R12: fused 3 aggr memsets into upd + pool 64-chunks: 1689->1608.
//  R13: last memset fused into pq: neutral (1612). Schedule harvested.
//  R14: upd was never tuned: 108us vs 40us traffic floor, LDS-capped at
//      4 blk/CU (33.8KB). Halve row-tile to 32 (16.9KB, acc<=32 AGPR) +
//      (256,6): streaming loads (no gathers) -> extra waves hide latency
//      without R9's L2-thrash mechanism. Tripwire: fail or >1660 -> revert.
//  R8(old): __builtin_nontemporal_* bypasses L2 on gfx950 -> never use.

#define EPSBN 1e-5f
#define TS 136   // bf16 elems per LDS row for 128-wide tiles (272 B = 17*16 B)
#define AS 264   // bf16 elems per LDS row for 256-wide tiles (528 B = 33*16 B)

typedef __bf16 bf16x8 __attribute__((ext_vector_type(8)));
typedef float floatx4 __attribute__((ext_vector_type(4)));
typedef float f32x2 __attribute__((ext_vector_type(2)));

#if __has_builtin(__builtin_elementwise_fma)
#define VFMA(a, b, c) __builtin_elementwise_fma((a), (b), (c))
#else
#define VFMA(a, b, c) ((a) * (b) + (c))
#endif
#if __has_builtin(__builtin_elementwise_max)
#define VMAX(a, b) __builtin_elementwise_max((a), (b))
#else
static __device__ __forceinline__ f32x2 VMAX(f32x2 a, f32x2 b) {
  f32x2 r; r.x = fmaxf(a.x, b.x); r.y = fmaxf(a.y, b.y); return r;
}
#endif

static __device__ __forceinline__ unsigned short f2b(float f) {
  union { float f; unsigned u; } v; v.f = f;
  unsigned u = v.u;
  return (unsigned short)((u + 0x7fffu + ((u >> 16) & 1u)) >> 16);  // RNE
}
static __device__ __forceinline__ unsigned pk2(float lo, float hi) {
  union { __hip_bfloat162 h; unsigned u; } v;
  v.h = __float22bfloat162_rn(make_float2(lo, hi));  // v_cvt_pk_bf16_f32
  return v.u;
}
static __device__ __forceinline__ float ubits(unsigned u) {
  union { unsigned u; float f; } v; v.u = u; return v.f;
}
static __device__ __forceinline__ f32x2 mk2(float a, float b) {
  f32x2 r; r.x = a; r.y = b; return r;
}
static __device__ __forceinline__ f32x2 sp2(float a) { return mk2(a, a); }
// unpack a packed bf16 pair (as u32) to f32x2 {lo, hi}
static __device__ __forceinline__ f32x2 up2(unsigned u) {
  return mk2(ubits(u << 16), ubits(u & 0xffff0000u));
}

// ---------------- fold BN into second linear, write transposed bf16 ----------------
__global__ __launch_bounds__(128) void fold_kernel(
    const float* __restrict__ mw2, const float* __restrict__ mb2,
    const float* __restrict__ mg, const float* __restrict__ mb,
    const float* __restrict__ mm, const float* __restrict__ mv,
    const float* __restrict__ uw2, const float* __restrict__ ub2,
    const float* __restrict__ ug, const float* __restrict__ ub,
    const float* __restrict__ um, const float* __restrict__ uv,
    unsigned short* __restrict__ mW2fT, float* __restrict__ mB2f,
    unsigned short* __restrict__ uW2fT, float* __restrict__ uB2f) {
  int l = blockIdx.x & 3;
  bool isu = blockIdx.x >= 4;
  const float* W2 = (isu ? uw2 : mw2) + (size_t)l * 128 * 128;
  const float* b2 = (isu ? ub2 : mb2) + l * 128;
  const float* gg = (isu ? ug : mg) + l * 128;
  const float* bb = (isu ? ub : mb) + l * 128;
  const float* mn = (isu ? um : mm) + l * 128;
  const float* vr = (isu ? uv : mv) + l * 128;
  unsigned short* WfT = (isu ? uW2fT : mW2fT) + (size_t)l * 128 * 128;
  float* Bf = (isu ? uB2f : mB2f) + l * 128;
  __shared__ float a[128], c[128];
  int d = threadIdx.x;
  float ad = gg[d] * rsqrtf(vr[d] + EPSBN);
  a[d] = ad;
  c[d] = bb[d] - mn[d] * ad;
  __syncthreads();
  float acc = b2[d];
  for (int k = 0; k < 128; ++k) {
    float w = W2[k * 128 + d];
    WfT[(size_t)d * 128 + k] = f2b(a[k] * w);  // [n][k] bf16
    acc = fmaf(c[k], w, acc);
  }
  Bf[d] = acc;
}

// ---------------- transpose W1ab / U1 to [n][k] bf16 ----------------
__global__ __launch_bounds__(256) void transp_kernel(
    const float* __restrict__ mw1, const float* __restrict__ uw1,
    unsigned short* __restrict__ W1abT, unsigned short* __restrict__ U1T) {
  int l = blockIdx.x & 3;
  bool isu = blockIdx.x >= 4;
  int tid = threadIdx.x;
  if (!isu) {
    const float* W = mw1 + (size_t)l * 260 * 128;
    unsigned short* T = W1abT + (size_t)l * 256 * 128;
    for (int i = tid; i < 256 * 128; i += 256) {
      int n = i >> 7, k = i & 127;
      float v = (n < 128) ? W[(size_t)k * 128 + n] : W[(size_t)(128 + k) * 128 + (n - 128)];
      T[i] = f2b(v);
    }
  } else {
    const float* W = uw1 + (size_t)l * 256 * 128;
    unsigned short* T = U1T + (size_t)l * 128 * 256;
    for (int i = tid; i < 128 * 256; i += 256) {
      int n = i >> 8, k = i & 255;
      T[i] = f2b(W[(size_t)k * 128 + n]);
    }
  }
}

// ---------------- input projection ----------------
__global__ __launch_bounds__(256) void lin_in_kernel(
    const float* __restrict__ x, const float* __restrict__ pos,
    const float* __restrict__ W, const float* __restrict__ b,
    float* __restrict__ h, int Nn) {
  int gi = blockIdx.x * 256 + threadIdx.x;
  if (gi >= Nn * 128) return;
  int n = gi >> 7, d = gi & 127;
  float acc = b[d];
#pragma unroll
  for (int j = 0; j < 11; ++j) acc = fmaf(x[(size_t)n * 11 + j], W[j * 128 + d], acc);
#pragma unroll
  for (int j = 0; j < 3; ++j) acc = fmaf(pos[(size_t)n * 3 + j], W[(11 + j) * 128 + d], acc);
  h[gi] = acc;
}

// ---------------- counting sort of edges by dst ----------------
__global__ __launch_bounds__(256) void hist_kernel(const int* __restrict__ dst, int* __restrict__ count, int Ee) {
  int i = blockIdx.x * 256 + threadIdx.x;
  if (i < Ee) atomicAdd(&count[dst[i]], 1);
}

// 3-kernel parallel exclusive scan over count[n] -> cursor[n]
__global__ __launch_bounds__(1024) void scan1_kernel(
    const int* __restrict__ count, int* __restrict__ cursor, int* __restrict__ bsum, int n) {
  __shared__ int buf[1024];
  int i = blockIdx.x * 1024 + threadIdx.x;
  int v = (i < n) ? count[i] : 0;
  buf[threadIdx.x] = v;
  __syncthreads();
  for (int off = 1; off < 1024; off <<= 1) {
    int t = (threadIdx.x >= off) ? buf[threadIdx.x - off] : 0;
    __syncthreads();
    buf[threadIdx.x] += t;
    __syncthreads();
  }
  if (i < n) cursor[i] = buf[threadIdx.x] - v;  // exclusive within block
  if (threadIdx.x == 1023) bsum[blockIdx.x] = buf[1023];
}
__global__ __launch_bounds__(1024) void scan2_kernel(int* __restrict__ bsum, int nb) {
  __shared__ int buf[1024];
  int v = (threadIdx.x < nb) ? bsum[threadIdx.x] : 0;
  buf[threadIdx.x] = v;
  __syncthreads();
  for (int off = 1; off < 1024; off <<= 1) {
    int t = (threadIdx.x >= off) ? buf[threadIdx.x - off] : 0;
    __syncthreads();
    buf[threadIdx.x] += t;
    __syncthreads();
  }
  if (threadIdx.x < nb) bsum[threadIdx.x] = buf[threadIdx.x] - v;  // exclusive
}
__global__ __launch_bounds__(1024) void scan3_kernel(
    int* __restrict__ cursor, const int* __restrict__ bsum, int n) {
  int i = blockIdx.x * 1024 + threadIdx.x;
  if (i < n) cursor[i] += bsum[blockIdx.x];
}

__global__ __launch_bounds__(256) void scatter_kernel(
    const int* __restrict__ src, const int* __restrict__ dst, const float* __restrict__ ea,
    int* __restrict__ cursor, int* __restrict__ dst_s, int* __restrict__ src_s,
    float* __restrict__ ea_s, int Ee) {
  int e = blockIdx.x * 256 + threadIdx.x;
  if (e >= Ee) return;
  int dn = dst[e];
  int pos = atomicAdd(&cursor[dn], 1);
  dst_s[pos] = dn;
  src_s[pos] = src[e];
  *(float4*)(ea_s + (size_t)pos * 4) = *(const float4*)(ea + (size_t)e * 4);
}

// per-64-edge-tile segment-start bitmask (bit i = edge 64T+i starts a run)
__global__ __launch_bounds__(256) void mask_kernel(
    const int* __restrict__ dst_s, unsigned long long* __restrict__ masks, int Ee, int nt) {
  int tile = blockIdx.x * 4 + (threadIdx.x >> 6);
  int lane = threadIdx.x & 63;
  if (tile >= nt) return;
  int e = tile * 64 + lane;
  bool start;
  if (e >= Ee || lane == 0) start = true;
  else start = (dst_s[e] != dst_s[e - 1]);
  unsigned long long m = __ballot(start);
  if (lane == 0) masks[tile] = m;
}

// ---------------- pq_kernel: P = h@W1a + b1 (folded), Q = h@W1b ----------------
// (standalone for layer 0; later layers fused into upd_kernel)
// Also zeroes this block's aggr rows for layer 0 (last memset fused away;
// race-free: one writer per row, edge launch is stream-ordered after).
__global__ __launch_bounds__(256, 4) void pq_kernel(
    const float* __restrict__ h, const unsigned short* __restrict__ W1abT,
    const float* __restrict__ b1n,
    unsigned short* __restrict__ P, unsigned short* __restrict__ Q,
    float* __restrict__ aggr, int Nn) {
  __shared__ unsigned short hs[64 * TS];
  const int tid = threadIdx.x;
  const int row0 = blockIdx.x * 64;
#pragma unroll
  for (int i = 0; i < 8; ++i) {
    int idx = tid + i * 256;
    int r = idx >> 5, c4 = (idx & 31) << 2;
    float4 v = make_float4(0.f, 0.f, 0.f, 0.f);
    if (row0 + r < Nn) {
      v = *(const float4*)(h + (size_t)(row0 + r) * 128 + c4);
      *(float4*)(aggr + (size_t)(row0 + r) * 128 + c4) = make_float4(0.f, 0.f, 0.f, 0.f);
    }
    *(uint2*)&hs[r * TS + c4] = make_uint2(pk2(v.x, v.y), pk2(v.z, v.w));
  }
  __syncthreads();
  const int lane = tid & 63, wv = tid >> 6;
  const int m16 = lane & 15, quad = lane >> 4;
  floatx4 acc[4][4];
#pragma unroll
  for (int mt = 0; mt < 4; ++mt)
#pragma unroll
    for (int nt = 0; nt < 4; ++nt) acc[mt][nt] = (floatx4)(0.0f);
  const __bf16* WT = (const __bf16*)W1abT;
  const __bf16* TlB = (const __bf16*)hs;
#pragma unroll
  for (int kb = 0; kb < 4; ++kb) {
    bf16x8 a[4], w[4];
#pragma unroll
    for (int mt = 0; mt < 4; ++mt)
      a[mt] = *(const bf16x8*)(TlB + (16 * mt + m16) * TS + kb * 32 + quad * 8);
#pragma unroll
    for (int nt = 0; nt < 4; ++nt)
      w[nt] = *(const bf16x8*)(WT + (size_t)(64 * wv + 16 * nt + m16) * 128 + kb * 32 + quad * 8);
#pragma unroll
    for (int mt = 0; mt < 4; ++mt)
#pragma unroll
      for (int nt = 0; nt < 4; ++nt)
        acc[mt][nt] = __builtin_amdgcn_mfma_f32_16x16x32_bf16(w[nt], a[mt], acc[mt][nt], 0, 0, 0);
  }
#pragma unroll
  for (int mt = 0; mt < 4; ++mt) {
    int row = row0 + 16 * mt + m16;
    if (row >= Nn) continue;
#pragma unroll
    for (int nt = 0; nt < 4; ++nt) {
      int n0 = 64 * wv + 16 * nt + 4 * quad;
      floatx4 A = acc[mt][nt];
      if (n0 < 128) {
        float4 bb = *(const float4*)(b1n + n0);
        uint2 o = make_uint2(pk2(A[0] + bb.x, A[1] + bb.y), pk2(A[2] + bb.z, A[3] + bb.w));
        *(uint2*)(P + (size_t)row * 128 + n0) = o;
      } else {
        uint2 o = make_uint2(pk2(A[0], A[1]), pk2(A[2], A[3]));
        *(uint2*)(Q + (size_t)row * 128 + (n0 - 128)) = o;
      }
    }
  }
}

// ---------------- edge kernel helpers ----------------
// Q-only prefetch: src is random -> these are the long-latency loads to hide.
static __device__ __forceinline__ void gather_q(
    const unsigned short* __restrict__ Q, const int* __restrict__ ssrcBase,
    int rw, int c0, uint4* qv) {
#pragma unroll
  for (int p = 0; p < 4; ++p) {
    int sna = ssrcBase[16 * p + rw];
    qv[p] = *(const uint4*)(Q + (size_t)sna * 128 + c0);
  }
}

// P loads inline: dst-sorted edges -> ~4 distinct dst rows per 64-edge tile,
// so these hit L1/L2. b1 is pre-folded into P (R9) -> no bias regs/adds here.
static __device__ __forceinline__ void build_T(
    unsigned short* __restrict__ TlBuf,
    const unsigned short* __restrict__ P, const uint4* qv,
    const int* __restrict__ sdstBase, const float* __restrict__ seaBase,
    const f32x2 (*__restrict__ wc2)[4], int rw, int c0) {
  uint4 pv[4];
#pragma unroll
  for (int p = 0; p < 4; ++p) {
    int dn = sdstBase[16 * p + rw];
    int dna = dn < 0 ? 0 : dn;
    pv[p] = *(const uint4*)(P + (size_t)dna * 128 + c0);
  }
#pragma unroll
  for (int p = 0; p < 4; ++p) {
    int row = 16 * p + rw;
    int dn = sdstBase[row];
    uint4 out = make_uint4(0u, 0u, 0u, 0u);
    if (dn >= 0) {
      float e0 = seaBase[row * 4 + 0], e1 = seaBase[row * 4 + 1];
      float e2 = seaBase[row * 4 + 2], e3 = seaBase[row * 4 + 3];
      unsigned pu[4] = {pv[p].x, pv[p].y, pv[p].z, pv[p].w};
      unsigned qu[4] = {qv[p].x, qv[p].y, qv[p].z, qv[p].w};
      unsigned ou[4];
#pragma unroll
      for (int g = 0; g < 4; ++g) {
        f32x2 t = up2(pu[g]) + up2(qu[g]);            // v_pk_add_f32
        t = VFMA(sp2(e0), wc2[0][g], t);              // v_pk_fma_f32
        t = VFMA(sp2(e1), wc2[1][g], t);
        t = VFMA(sp2(e2), wc2[2][g], t);
        t = VFMA(sp2(e3), wc2[3][g], t);
        t = VMAX(t, sp2(0.f));                        // v_pk_max_f32
        ou[g] = pk2(t.x, t.y);
      }
      out = make_uint4(ou[0], ou[1], ou[2], ou[3]);
    }
    *(uint4*)&TlBuf[row * TS + c0] = out;
  }
}

// W2 fragments streamed from global (L2-resident 32 KB) -> no persistent regs
static __device__ __forceinline__ void mfma_B(
    const unsigned short* __restrict__ TlBuf, const __bf16* __restrict__ WT,
    int m16, int quad, int wv, floatx4 acc[4][2]) {
#pragma unroll
  for (int mt = 0; mt < 4; ++mt) { acc[mt][0] = (floatx4)(0.0f); acc[mt][1] = (floatx4)(0.0f); }
  const __bf16* TlB = (const __bf16*)TlBuf;
#pragma unroll
  for (int kb = 0; kb < 4; ++kb) {
    bf16x8 w0 = *(const bf16x8*)(WT + (size_t)(32 * wv + m16) * 128 + kb * 32 + quad * 8);
    bf16x8 w1 = *(const bf16x8*)(WT + (size_t)(32 * wv + 16 + m16) * 128 + kb * 32 + quad * 8);
    bf16x8 a[4];
#pragma unroll
    for (int mt = 0; mt < 4; ++mt)
      a[mt] = *(const bf16x8*)(TlB + (16 * mt + m16) * TS + kb * 32 + quad * 8);
#pragma unroll
    for (int mt = 0; mt < 4; ++mt) {
      acc[mt][0] = __builtin_amdgcn_mfma_f32_16x16x32_bf16(w0, a[mt], acc[mt][0], 0, 0, 0);
      acc[mt][1] = __builtin_amdgcn_mfma_f32_16x16x32_bf16(w1, a[mt], acc[mt][1], 0, 0, 0);
    }
  }
}

static __device__ __forceinline__ void epi_m(
    unsigned short* __restrict__ TlBuf, floatx4 acc[4][2],
    const float* __restrict__ B2f, int m16, int quad, int wv) {
  int n0 = 32 * wv + 4 * quad;
  float4 b0 = *(const float4*)(B2f + n0);
  float4 b1q = *(const float4*)(B2f + n0 + 16);
  f32x2 bz0 = mk2(b0.x, b0.y), bz1 = mk2(b0.z, b0.w);
  f32x2 bz2 = mk2(b1q.x, b1q.y), bz3 = mk2(b1q.z, b1q.w);
#pragma unroll
  for (int mt = 0; mt < 4; ++mt) {
    int row = 16 * mt + m16;
    floatx4 A0 = acc[mt][0], A1 = acc[mt][1];
    f32x2 t0 = VMAX(mk2(A0[0], A0[1]) + bz0, sp2(0.f));
    f32x2 t1 = VMAX(mk2(A0[2], A0[3]) + bz1, sp2(0.f));
    f32x2 t2 = VMAX(mk2(A1[0], A1[1]) + bz2, sp2(0.f));
    f32x2 t3 = VMAX(mk2(A1[2], A1[3]) + bz3, sp2(0.f));
    *(uint2*)&TlBuf[row * TS + n0] = make_uint2(pk2(t0.x, t0.y), pk2(t1.x, t1.y));
    *(uint2*)&TlBuf[row * TS + n0 + 16] = make_uint2(pk2(t2.x, t2.y), pk2(t3.x, t3.y));
  }
}

// mask-driven segmented reduce; thread covers cols c4..c4+3 and 64+c4..64+c4+3
// -> each store across 16 consecutive lanes is a fully-covered 256-B group
// (R3 lesson: 32-B/lane stride-32 stores write-amplified 137->334 MB).
static __device__ __forceinline__ void seg_reduce(
    const unsigned short* __restrict__ TlBuf, const int* __restrict__ sdstBase,
    unsigned long long mask, float* __restrict__ aggr, int tid) {
  const int c4 = (tid & 15) << 2;
  const int st = tid >> 4;
  const int dfirst = sdstBase[0], dlast = sdstBase[63];
  for (int s = st; s < 64; s += 16) {
    if (!(mask & (1ull << s))) continue;
    int dn = sdstBase[s];
    if (dn < 0) continue;
    int end;
    if (s >= 63) end = 64;
    else {
      unsigned long long m2 = mask >> (s + 1);
      end = m2 ? (s + 1 + (int)__builtin_ctzll(m2)) : 64;
    }
    f32x2 a0 = sp2(0.f), a1 = sp2(0.f), a2 = sp2(0.f), a3 = sp2(0.f);
    for (int e = s; e < end; ++e) {
      uint2 v1 = *(const uint2*)&TlBuf[e * TS + c4];
      uint2 v2 = *(const uint2*)&TlBuf[e * TS + 64 + c4];
      a0 += up2(v1.x); a1 += up2(v1.y);
      a2 += up2(v2.x); a3 += up2(v2.y);
    }
    float* ap = aggr + (size_t)dn * 128 + c4;
    if (dn == dfirst || dn == dlast) {
      atomicAdd(ap + 0, a0.x); atomicAdd(ap + 1, a0.y);
      atomicAdd(ap + 2, a1.x); atomicAdd(ap + 3, a1.y);
      atomicAdd(ap + 64, a2.x); atomicAdd(ap + 65, a2.y);
      atomicAdd(ap + 66, a3.x); atomicAdd(ap + 67, a3.y);
    } else {
      *(float4*)ap = make_float4(a0.x, a0.y, a1.x, a1.y);
      *(float4*)(ap + 64) = make_float4(a2.x, a2.y, a3.x, a3.y);
    }
  }
}

// ---------------- edge message kernel: 1 tile/block, 4 barriers, 5 waves/SIMD ----------------
__global__ __launch_bounds__(256, 5) void edge_kernel(
    const unsigned short* __restrict__ P, const unsigned short* __restrict__ Q,
    const float* __restrict__ ea_s, const int* __restrict__ dst_s, const int* __restrict__ src_s,
    const unsigned long long* __restrict__ masks,
    const float* __restrict__ W1c,
    const unsigned short* __restrict__ W2fT, const float* __restrict__ B2f,
    float* __restrict__ aggr, int Ee, int nT) {
  __shared__ unsigned short Tl[64 * TS];   // 17.4 KB
  __shared__ float sea[64 * 4];            // 1 KB
  __shared__ int sdst[64], ssrc[64];       // 0.5 KB
  const int tid = threadIdx.x;
  // XCD swizzle: blocks round-robin over 8 XCDs; give each XCD a contiguous
  // range of edge tiles (perf heuristic only — any mapping is correct).
  int b = blockIdx.x;
  const int nB = gridDim.x;
  const int per = nB >> 3;
  if (b < (per << 3)) b = (b & 7) * per + (b >> 3);
  const int e0 = b * 64;
  const unsigned long long mask0 = masks[b];
  if (tid < 64) {
    int e = e0 + tid;
    bool ok = e < Ee;
    sdst[tid] = ok ? dst_s[e] : -1;
    ssrc[tid] = ok ? src_s[e] : 0;
  } else if (tid < 128) {
    int r = tid - 64;
    int e = e0 + r;
    float4 ev = (e < Ee) ? *(const float4*)(ea_s + (size_t)e * 4)
                         : make_float4(0.f, 0.f, 0.f, 0.f);
    *(float4*)&sea[r * 4] = ev;
  }
  const int lane = tid & 63, wv = tid >> 6;
  const int m16 = lane & 15, quad = lane >> 4;
  const int rw = tid >> 4, c0 = (tid & 15) << 3;

  // per-thread W1c slice (packed pairs); b1 is pre-folded into P
  f32x2 wc2[4][4];
#pragma unroll
  for (int r = 0; r < 4; ++r) {
    float4 u = *(const float4*)(W1c + r * 128 + c0);
    float4 v = *(const float4*)(W1c + r * 128 + c0 + 4);
    wc2[r][0] = mk2(u.x, u.y); wc2[r][1] = mk2(u.z, u.w);
    wc2[r][2] = mk2(v.x, v.y); wc2[r][3] = mk2(v.z, v.w);
  }
  const __bf16* WT = (const __bf16*)W2fT;
  __syncthreads();                                             // meta ready

  uint4 qv[4];
  gather_q(Q, ssrc, rw, c0, qv);                               // random-src gathers
  build_T(Tl, P, qv, sdst, sea, wc2, rw, c0);                  // t -> Tl
  __syncthreads();                                             // Tl ready

  floatx4 acc[4][2];
  mfma_B(Tl, WT, m16, quad, wv, acc);                          // m = t@W2f
  __syncthreads();                                             // Tl reads done

  epi_m(Tl, acc, B2f, m16, quad, wv);                          // m -> Tl (bf16)
  __syncthreads();                                             // m ready

  seg_reduce(Tl, sdst, mask0, aggr, tid);                      // -> aggr
}

// ---------------- fused update MLP (+ next-layer P'/Q + aggr re-zero) ----------------
// 32-row tiles (R14): LDS 16.9KB -> 6 blocks/CU; acc<=32 AGPR -> (256,6).
__global__ __launch_bounds__(256, 6) void upd_kernel(
    float* __restrict__ h, float* __restrict__ aggr,
    const unsigned short* __restrict__ U1T, const float* __restrict__ ub1,
    const unsigned short* __restrict__ uW2fT, const float* __restrict__ uB2f, int Nn,
    const unsigned short* __restrict__ W1abT_next, const float* __restrict__ b1_next,
    unsigned short* __restrict__ P, unsigned short* __restrict__ Q) {
  __shared__ unsigned short as_[32 * AS];  // [h|aggr]; u1 overlay; then h_new overlay
  const int tid = threadIdx.x;
  const int row0 = blockIdx.x * 32;
#pragma unroll
  for (int i = 0; i < 4; ++i) {
    int idx = tid + i * 256;
    int r = idx >> 5, c4 = (idx & 31) << 2;
    float4 v = make_float4(0.f, 0.f, 0.f, 0.f);
    if (row0 + r < Nn) v = *(const float4*)(h + (size_t)(row0 + r) * 128 + c4);
    *(uint2*)&as_[r * AS + c4] = make_uint2(pk2(v.x, v.y), pk2(v.z, v.w));
  }
#pragma unroll
  for (int i = 0; i < 4; ++i) {
    int idx = tid + i * 256;
    int r = idx >> 5, c4 = (idx & 31) << 2;
    float4 v = make_float4(0.f, 0.f, 0.f, 0.f);
    if (row0 + r < Nn) {
      float* ap = aggr + (size_t)(row0 + r) * 128 + c4;
      v = *(const float4*)ap;
      // fused re-zero for next layer's edge pass (race-free: this block is
      // the only reader of these rows, and the next edge launch is stream-
      // ordered after this kernel).
      if (W1abT_next) *(float4*)ap = make_float4(0.f, 0.f, 0.f, 0.f);
    }
    *(uint2*)&as_[r * AS + 128 + c4] = make_uint2(pk2(v.x, v.y), pk2(v.z, v.w));
  }
  __syncthreads();
  const int lane = tid & 63, wv = tid >> 6;
  const int m16 = lane & 15, quad = lane >> 4;
  const __bf16* asB = (const __bf16*)as_;
  unsigned short* u1s = as_;  // overlay (TS stride)
  // pass 1: u1 = relu([h|aggr]@U1 + ub1), K=256
  {
    floatx4 acc[2][2];
#pragma unroll
    for (int mt = 0; mt < 2; ++mt) { acc[mt][0] = (floatx4)(0.0f); acc[mt][1] = (floatx4)(0.0f); }
    const __bf16* WT = (const __bf16*)U1T;
#pragma unroll
    for (int kb = 0; kb < 8; ++kb) {
      bf16x8 w0 = *(const bf16x8*)(WT + (size_t)(32 * wv + m16) * 256 + kb * 32 + quad * 8);
      bf16x8 w1 = *(const bf16x8*)(WT + (size_t)(32 * wv + 16 + m16) * 256 + kb * 32 + quad * 8);
      bf16x8 a[2];
#pragma unroll
      for (int mt = 0; mt < 2; ++mt)
        a[mt] = *(const bf16x8*)(asB + (16 * mt + m16) * AS + kb * 32 + quad * 8);
#pragma unroll
      for (int mt = 0; mt < 2; ++mt) {
        acc[mt][0] = __builtin_amdgcn_mfma_f32_16x16x32_bf16(w0, a[mt], acc[mt][0], 0, 0, 0);
        acc[mt][1] = __builtin_amdgcn_mfma_f32_16x16x32_bf16(w1, a[mt], acc[mt][1], 0, 0, 0);
      }
    }
    __syncthreads();  // pass-1 reads of as_ complete -> safe to overlay u1
    int n0 = 32 * wv + 4 * quad;
    float4 bv0 = *(const float4*)(ub1 + n0);
    float4 bv1 = *(const float4*)(ub1 + n0 + 16);
#pragma unroll
    for (int mt = 0; mt < 2; ++mt) {
      int row = 16 * mt + m16;
      floatx4 A0 = acc[mt][0], A1 = acc[mt][1];
      *(uint2*)&u1s[row * TS + n0] =
          make_uint2(pk2(fmaxf(A0[0] + bv0.x, 0.f), fmaxf(A0[1] + bv0.y, 0.f)),
                     pk2(fmaxf(A0[2] + bv0.z, 0.f), fmaxf(A0[3] + bv0.w, 0.f)));
      *(uint2*)&u1s[row * TS + n0 + 16] =
          make_uint2(pk2(fmaxf(A1[0] + bv1.x, 0.f), fmaxf(A1[1] + bv1.y, 0.f)),
                     pk2(fmaxf(A1[2] + bv1.z, 0.f), fmaxf(A1[3] + bv1.w, 0.f)));
    }
  }
  __syncthreads();
  // pass 2: h_new = h + relu(u1@U2f + uB2f), K=128; write global + LDS bf16
  {
    floatx4 acc[2][2];
#pragma unroll
    for (int mt = 0; mt < 2; ++mt) { acc[mt][0] = (floatx4)(0.0f); acc[mt][1] = (floatx4)(0.0f); }
    const __bf16* WT = (const __bf16*)uW2fT;
    const __bf16* u1B = (const __bf16*)u1s;
#pragma unroll
    for (int kb = 0; kb < 4; ++kb) {
      bf16x8 w0 = *(const bf16x8*)(WT + (size_t)(32 * wv + m16) * 128 + kb * 32 + quad * 8);
      bf16x8 w1 = *(const bf16x8*)(WT + (size_t)(32 * wv + 16 + m16) * 128 + kb * 32 + quad * 8);
      bf16x8 a[2];
#pragma unroll
      for (int mt = 0; mt < 2; ++mt)
        a[mt] = *(const bf16x8*)(u1B + (16 * mt + m16) * TS + kb * 32 + quad * 8);
#pragma unroll
      for (int mt = 0; mt < 2; ++mt) {
        acc[mt][0] = __builtin_amdgcn_mfma_f32_16x16x32_bf16(w0, a[mt], acc[mt][0], 0, 0, 0);
        acc[mt][1] = __builtin_amdgcn_mfma_f32_16x16x32_bf16(w1, a[mt], acc[mt][1], 0, 0, 0);
      }
    }
    __syncthreads();  // pass-2 reads of u1s complete -> safe to overlay h_new
    int n0 = 32 * wv + 4 * quad;
    float4 bv0 = *(const float4*)(uB2f + n0);
    float4 bv1 = *(const float4*)(uB2f + n0 + 16);
#pragma unroll
    for (int mt = 0; mt < 2; ++mt) {
      int rloc = 16 * mt + m16;
      int row = row0 + rloc;
      floatx4 A0 = acc[mt][0], A1 = acc[mt][1];
      if (row < Nn) {
        float* hp0 = h + (size_t)row * 128 + n0;
        float4 hv0 = *(float4*)hp0;
        float4 o0 = make_float4(hv0.x + fmaxf(A0[0] + bv0.x, 0.f), hv0.y + fmaxf(A0[1] + bv0.y, 0.f),
                                hv0.z + fmaxf(A0[2] + bv0.z, 0.f), hv0.w + fmaxf(A0[3] + bv0.w, 0.f));
        *(float4*)hp0 = o0;
        float* hp1 = hp0 + 16;
        float4 hv1 = *(float4*)hp1;
        float4 o1 = make_float4(hv1.x + fmaxf(A1[0] + bv1.x, 0.f), hv1.y + fmaxf(A1[1] + bv1.y, 0.f),
                                hv1.z + fmaxf(A1[2] + bv1.z, 0.f), hv1.w + fmaxf(A1[3] + bv1.w, 0.f));
        *(float4*)hp1 = o1;
        if (W1abT_next) {
          *(uint2*)&u1s[rloc * TS + n0] = make_uint2(pk2(o0.x, o0.y), pk2(o0.z, o0.w));
          *(uint2*)&u1s[rloc * TS + n0 + 16] = make_uint2(pk2(o1.x, o1.y), pk2(o1.z, o1.w));
        }
      } else if (W1abT_next) {
        *(uint2*)&u1s[rloc * TS + n0] = make_uint2(0u, 0u);
        *(uint2*)&u1s[rloc * TS + n0 + 16] = make_uint2(0u, 0u);
      }
    }
  }
  // fused next-layer P'/Q from h_new tile in LDS (b1_next folded into P)
  if (W1abT_next) {
    __syncthreads();
    floatx4 pacc[2][4];
#pragma unroll
    for (int mt = 0; mt < 2; ++mt)
#pragma unroll
      for (int nt = 0; nt < 4; ++nt) pacc[mt][nt] = (floatx4)(0.0f);
    const __bf16* WT = (const __bf16*)W1abT_next;
    const __bf16* hB = (const __bf16*)u1s;
#pragma unroll
    for (int kb = 0; kb < 4; ++kb) {
      bf16x8 a[2], w[4];
#pragma unroll
      for (int mt = 0; mt < 2; ++mt)
        a[mt] = *(const bf16x8*)(hB + (16 * mt + m16) * TS + kb * 32 + quad * 8);
#pragma unroll
      for (int nt = 0; nt < 4; ++nt)
        w[nt] = *(const bf16x8*)(WT + (size_t)(64 * wv + 16 * nt + m16) * 128 + kb * 32 + quad * 8);
#pragma unroll
      for (int mt = 0; mt < 2; ++mt)
#pragma unroll
        for (int nt = 0; nt < 4; ++nt)
          pacc[mt][nt] = __builtin_amdgcn_mfma_f32_16x16x32_bf16(w[nt], a[mt], pacc[mt][nt], 0, 0, 0);
    }
#pragma unroll
    for (int mt = 0; mt < 2; ++mt) {
      int row = row0 + 16 * mt + m16;
      if (row >= Nn) continue;
#pragma unroll
      for (int nt = 0; nt < 4; ++nt) {
        int n0 = 64 * wv + 16 * nt + 4 * quad;
        floatx4 A = pacc[mt][nt];
        if (n0 < 128) {
          float4 bb = *(const float4*)(b1_next + n0);
          uint2 o = make_uint2(pk2(A[0] + bb.x, A[1] + bb.y), pk2(A[2] + bb.z, A[3] + bb.w));
          *(uint2*)(P + (size_t)row * 128 + n0) = o;
        } else {
          uint2 o = make_uint2(pk2(A[0], A[1]), pk2(A[2], A[3]));
          *(uint2*)(Q + (size_t)row * 128 + (n0 - 128)) = o;
        }
      }
    }
  }
}

// ---------------- pooling (64-node chunks: 4x shorter serial chain) ----------------
__global__ __launch_bounds__(128) void pool_sum_kernel(
    const float* __restrict__ h, const int* __restrict__ batch,
    float* __restrict__ sums, int* __restrict__ gcnt, int Nn) {
  int n0 = blockIdx.x * 64;
  if (n0 >= Nn) return;
  int nend = min(n0 + 64, Nn);
  int d = threadIdx.x;
  int gcur = batch[n0];
  float run = 0.f;
  int cnt = 0;
  for (int n = n0; n < nend; ++n) {
    int g = batch[n];
    if (g != gcur) {
      atomicAdd(&sums[(size_t)gcur * 128 + d], run);
      if (d == 0) atomicAdd(&gcnt[gcur], cnt);
      run = 0.f; cnt = 0; gcur = g;
    }
    run += h[(size_t)n * 128 + d];
    cnt += 1;
  }
  atomicAdd(&sums[(size_t)gcur * 128 + d], run);
  if (d == 0) atomicAdd(&gcnt[gcur], cnt);
}

__global__ __launch_bounds__(128) void pred_kernel(
    const float* __restrict__ sums, const int* __restrict__ gcnt,
    const float* __restrict__ pw, const float* __restrict__ pb, float* __restrict__ out) {
  __shared__ float red[2];
  int g = blockIdx.x, d = threadIdx.x;
  float c = fmaxf((float)gcnt[g], 1.f);
  float v = (sums[(size_t)g * 128 + d] / c) * pw[d];
  for (int o = 32; o > 0; o >>= 1) v += __shfl_down(v, o, 64);
  if ((d & 63) == 0) red[d >> 6] = v;
  __syncthreads();
  if (d == 0) out[g] = red[0] + red[1] + pb[0];
}

// ---------------- launch ----------------
extern "C" void kernel_launch(void* const* d_in, const int* in_sizes, int n_in,
                              void* d_out, int out_size, void* d_ws, size_t ws_size,
                              hipStream_t stream) {
  const float* x = (const float*)d_in[0];
  const float* pos = (const float*)d_in[1];
  const int* ei = (const int*)d_in[2];
  const float* ea = (const float*)d_in[3];
  const int* batch = (const int*)d_in[4];
  const float* lin_w = (const float*)d_in[5];
  const float* lin_b = (const float*)d_in[6];
  const float* mw1 = (const float*)d_in[7];
  const float* mb1 = (const float*)d_in[8];
  const float* mg = (const float*)d_in[9];
  const float* mbb = (const float*)d_in[10];
  const float* mm = (const float*)d_in[11];
  const float* mv = (const float*)d_in[12];
  const float* mw2 = (const float*)d_in[13];
  const float* mb2 = (const float*)d_in[14];
  const float* uw1 = (const float*)d_in[15];
  const float* ub1 = (const float*)d_in[16];
  const float* ug = (const float*)d_in[17];
  const float* ubb = (const float*)d_in[18];
  const float* um = (const float*)d_in[19];
  const float* uv = (const float*)d_in[20];
  const float* uw2 = (const float*)d_in[21];
  const float* ub2 = (const float*)d_in[22];
  const float* pw = (const float*)d_in[23];
  const float* pb = (const float*)d_in[24];
  float* out = (float*)d_out;

  const int Nn = in_sizes[0] / 11;
  const int Ee = in_sizes[3] / 4;
  const int* srcp = ei;        // edge_index[0] = source j
  const int* dstp = ei + Ee;   // edge_index[1] = target i

  char* wsb = (char*)d_ws;
  size_t off = 0;
  auto alloc = [&](size_t bytes) -> void* {
    void* p = wsb + off;
    off = (off + bytes + 255) & ~(size_t)255;
    return p;
  };
  float* h = (float*)alloc((size_t)Nn * 128 * 4);
  unsigned short* Pb = (unsigned short*)alloc((size_t)Nn * 128 * 2);
  unsigned short* Qb = (unsigned short*)alloc((size_t)Nn * 128 * 2);
  float* aggr = (float*)alloc((size_t)Nn * 128 * 4);
  int* dst_s = (int*)alloc((size_t)Ee * 4);
  int* src_s = (int*)alloc((size_t)Ee * 4);
  float* ea_s = (float*)alloc((size_t)Ee * 16);
  int* count = (int*)alloc((size_t)Nn * 4);
  int* cursor = (int*)alloc((size_t)Nn * 4);
  int* bsum = (int*)alloc((size_t)1024 * 4);
  const int nTiles = (Ee + 63) / 64;
  unsigned long long* masks = (unsigned long long*)alloc((size_t)nTiles * 8);
  unsigned short* mW2fT = (unsigned short*)alloc((size_t)4 * 128 * 128 * 2);
  unsigned short* uW2fT = (unsigned short*)alloc((size_t)4 * 128 * 128 * 2);
  unsigned short* W1abT = (unsigned short*)alloc((size_t)4 * 256 * 128 * 2);
  unsigned short* U1T = (unsigned short*)alloc((size_t)4 * 128 * 256 * 2);
  float* mB2f = (float*)alloc((size_t)4 * 128 * 4);
  float* uB2f = (float*)alloc((size_t)4 * 128 * 4);
  float* sums = (float*)alloc((size_t)out_size * 128 * 4);
  int* gcnt = (int*)alloc((size_t)out_size * 4);
  (void)ws_size; (void)n_in;

  fold_kernel<<<8, 128, 0, stream>>>(mw2, mb2, mg, mbb, mm, mv,
                                     uw2, ub2, ug, ubb, um, uv,
                                     mW2fT, mB2f, uW2fT, uB2f);
  transp_kernel<<<8, 256, 0, stream>>>(mw1, uw1, W1abT, U1T);
  lin_in_kernel<<<(Nn * 128 + 255) / 256, 256, 0, stream>>>(x, pos, lin_w, lin_b, h, Nn);

  hipMemsetAsync(count, 0, (size_t)Nn * 4, stream);
  hist_kernel<<<(Ee + 255) / 256, 256, 0, stream>>>(dstp, count, Ee);
  const int NB = (Nn + 1023) / 1024;
  scan1_kernel<<<NB, 1024, 0, stream>>>(count, cursor, bsum, Nn);
  scan2_kernel<<<1, 1024, 0, stream>>>(bsum, NB);
  scan3_kernel<<<NB, 1024, 0, stream>>>(cursor, bsum, Nn);
  scatter_kernel<<<(Ee + 255) / 256, 256, 0, stream>>>(srcp, dstp, ea, cursor,
                                                       dst_s, src_s, ea_s, Ee);
  mask_kernel<<<(nTiles + 3) / 4, 256, 0, stream>>>(dst_s, masks, Ee, nTiles);

  const int gN = (Nn + 63) / 64;
  const int gU = (Nn + 31) / 32;
  // pq also zeroes layer-0 aggr rows (last big memset fused away)
  pq_kernel<<<gN, 256, 0, stream>>>(h, W1abT, mb1, Pb, Qb, aggr, Nn);
  for (int l = 0; l < 4; ++l) {                                  // upd re-zeros for l=1..3
    edge_kernel<<<nTiles, 256, 0, stream>>>(
        Pb, Qb, ea_s, dst_s, src_s, masks,
        mw1 + (size_t)l * 260 * 128 + 256 * 128,
        mW2fT + (size_t)l * 16384, mB2f + l * 128, aggr, Ee, nTiles);
    upd_kernel<<<gU, 256, 0, stream>>>(
        h, aggr, U1T + (size_t)l * 128 * 256, ub1 + l * 128,
        uW2fT + (size_t)l * 16384, uB2f + l * 128, Nn,
        (l < 3) ? (W1abT + (size_t)(l + 1) * 256 * 128) : nullptr,
        (l < 3) ? (mb1 + (size_t)(l + 1) * 128) : nullptr, Pb, Qb);
  }

  hipMemsetAsync(sums, 0, (size_t)out_size * 128 * 4, stream);
  hipMemsetAsync(gcnt, 0, (size_t)out_size * 4, stream);
  pool_sum_kernel<<<(Nn + 63) / 64, 128, 0, stream>>>(h, batch, sums, gcnt, Nn);
  pred_kernel<<<out_size, 128, 0, stream>>>(sums, gcnt, pw, pb, out);
}

// Round 15
// 1598.594 us; speedup vs baseline: 1.0127x; 1.0127x over previous
//
#include <hip/hip_runtime.h>
#include <hip/hip_bf16.h>

// MPNN: N=100000 nodes, E=1600000 edges, D=128, L=4, G=64.
// All GEMM-shaped work on MFMA bf16 (fp32 accumulate), fp32 residual stream h.
//   prep: fold BN into W2 (both MLPs), transpose all B-matrices to [n][k] bf16,
//         counting-sort edges by dst, per-64-edge-tile segment-start bitmasks.
//   per layer:
//     edge_kernel (1 tile/block, 4 barriers, XCD-swizzled, packed-f32 VALU,
//         Q-only register prefetch, b1 pre-folded into P, ~19KB LDS, (256,5)):
//         t = relu(P'[dst]+Q[src]+ea@W1c) -> bf16 LDS (Tl)   [P' = h@W1a + b1]
//         m = relu(t@W2f+b2f)   (MFMA, W2 from L2) -> written back into Tl
//         mask-driven segmented reduce -> aggr (256-B-contiguous store groups)
//     upd_kernel (64-row tiles, (256,4)):
//                  u1 = relu([h|aggr]@U1+ub1) (MFMA K=256) -> bf16 LDS overlay
//                  h += relu(u1@U2f+uB2f)     (MFMA K=128), in-place
//                  + fused next-layer P'/Q = h_new @ W1ab (+b1_next on P)
//                  + fused aggr re-zero for the next layer (replaces memsets)
//     pq_kernel additionally zeroes layer-0 aggr (last memset fused away).
// XCD swizzle: default dispatch round-robins blocks over 8 XCDs; remap
// b -> (b&7)*per + (b>>3) so each XCD owns a contiguous edge range -> its
// P-gather slice (~3.2MB) fits the 4MB per-XCD L2; aggr writes XCD-local.
// Ledger:
//  R1: persistent blocks + per-XCD atomic counters tripled hbm_bytes ->
//      static blocks. Packed f32x2 VALU verified -> kept.
//  R3: VALU cuts alone don't move latency-bound edge; 256-B store groups.
//  R4/R8: launch_bounds below unified (arch+acc) demand SPILLS (hbm 3-6x).
//  R5/R7: Q-only prefetch + 1-tile blocks + (256,5): edge 239, occ 46.5.
//  R9: edge at 6 waves/SIMD thrashes per-XCD L2 (hbm 0.35->0.62) ->
//      edge occupancy optimum is 5 waves/SIMD. Edge is FROZEN since R10.
//  R10: b1-fold into P: edge 234.5. R11: upd/pq bounds neutral.
//  R12: fused 3 aggr memsets into upd + pool 64-chunks: 1689->1608.
//  R13: last memset fused into pq: neutral (1612). Schedule harvested.
//  R14: upd 32-row tiles REGRESSED (1619): 2x blocks => 2x full-weight
//      L2 re-reads per layer; occupancy gain cancelled. upd is structure-
//      bound (barriers + weight reload), not wave-starved.
//  R15: revert upd to the R12/R13-verified 64-row form. Best family locked:
//      1608-1612. All levers now bisected both directions; structural floor.
//  R8(old): __builtin_nontemporal_* bypasses L2 on gfx950 -> never use.

#define EPSBN 1e-5f
#define TS 136   // bf16 elems per LDS row for 128-wide tiles (272 B = 17*16 B)
#define AS 264   // bf16 elems per LDS row for 256-wide tiles (528 B = 33*16 B)

typedef __bf16 bf16x8 __attribute__((ext_vector_type(8)));
typedef float floatx4 __attribute__((ext_vector_type(4)));
typedef float f32x2 __attribute__((ext_vector_type(2)));

#if __has_builtin(__builtin_elementwise_fma)
#define VFMA(a, b, c) __builtin_elementwise_fma((a), (b), (c))
#else
#define VFMA(a, b, c) ((a) * (b) + (c))
#endif
#if __has_builtin(__builtin_elementwise_max)
#define VMAX(a, b) __builtin_elementwise_max((a), (b))
#else
static __device__ __forceinline__ f32x2 VMAX(f32x2 a, f32x2 b) {
  f32x2 r; r.x = fmaxf(a.x, b.x); r.y = fmaxf(a.y, b.y); return r;
}
#endif

static __device__ __forceinline__ unsigned short f2b(float f) {
  union { float f; unsigned u; } v; v.f = f;
  unsigned u = v.u;
  return (unsigned short)((u + 0x7fffu + ((u >> 16) & 1u)) >> 16);  // RNE
}
static __device__ __forceinline__ unsigned pk2(float lo, float hi) {
  union { __hip_bfloat162 h; unsigned u; } v;
  v.h = __float22bfloat162_rn(make_float2(lo, hi));  // v_cvt_pk_bf16_f32
  return v.u;
}
static __device__ __forceinline__ float ubits(unsigned u) {
  union { unsigned u; float f; } v; v.u = u; return v.f;
}
static __device__ __forceinline__ f32x2 mk2(float a, float b) {
  f32x2 r; r.x = a; r.y = b; return r;
}
static __device__ __forceinline__ f32x2 sp2(float a) { return mk2(a, a); }
// unpack a packed bf16 pair (as u32) to f32x2 {lo, hi}
static __device__ __forceinline__ f32x2 up2(unsigned u) {
  return mk2(ubits(u << 16), ubits(u & 0xffff0000u));
}

// ---------------- fold BN into second linear, write transposed bf16 ----------------
__global__ __launch_bounds__(128) void fold_kernel(
    const float* __restrict__ mw2, const float* __restrict__ mb2,
    const float* __restrict__ mg, const float* __restrict__ mb,
    const float* __restrict__ mm, const float* __restrict__ mv,
    const float* __restrict__ uw2, const float* __restrict__ ub2,
    const float* __restrict__ ug, const float* __restrict__ ub,
    const float* __restrict__ um, const float* __restrict__ uv,
    unsigned short* __restrict__ mW2fT, float* __restrict__ mB2f,
    unsigned short* __restrict__ uW2fT, float* __restrict__ uB2f) {
  int l = blockIdx.x & 3;
  bool isu = blockIdx.x >= 4;
  const float* W2 = (isu ? uw2 : mw2) + (size_t)l * 128 * 128;
  const float* b2 = (isu ? ub2 : mb2) + l * 128;
  const float* gg = (isu ? ug : mg) + l * 128;
  const float* bb = (isu ? ub : mb) + l * 128;
  const float* mn = (isu ? um : mm) + l * 128;
  const float* vr = (isu ? uv : mv) + l * 128;
  unsigned short* WfT = (isu ? uW2fT : mW2fT) + (size_t)l * 128 * 128;
  float* Bf = (isu ? uB2f : mB2f) + l * 128;
  __shared__ float a[128], c[128];
  int d = threadIdx.x;
  float ad = gg[d] * rsqrtf(vr[d] + EPSBN);
  a[d] = ad;
  c[d] = bb[d] - mn[d] * ad;
  __syncthreads();
  float acc = b2[d];
  for (int k = 0; k < 128; ++k) {
    float w = W2[k * 128 + d];
    WfT[(size_t)d * 128 + k] = f2b(a[k] * w);  // [n][k] bf16
    acc = fmaf(c[k], w, acc);
  }
  Bf[d] = acc;
}

// ---------------- transpose W1ab / U1 to [n][k] bf16 ----------------
__global__ __launch_bounds__(256) void transp_kernel(
    const float* __restrict__ mw1, const float* __restrict__ uw1,
    unsigned short* __restrict__ W1abT, unsigned short* __restrict__ U1T) {
  int l = blockIdx.x & 3;
  bool isu = blockIdx.x >= 4;
  int tid = threadIdx.x;
  if (!isu) {
    const float* W = mw1 + (size_t)l * 260 * 128;
    unsigned short* T = W1abT + (size_t)l * 256 * 128;
    for (int i = tid; i < 256 * 128; i += 256) {
      int n = i >> 7, k = i & 127;
      float v = (n < 128) ? W[(size_t)k * 128 + n] : W[(size_t)(128 + k) * 128 + (n - 128)];
      T[i] = f2b(v);
    }
  } else {
    const float* W = uw1 + (size_t)l * 256 * 128;
    unsigned short* T = U1T + (size_t)l * 128 * 256;
    for (int i = tid; i < 128 * 256; i += 256) {
      int n = i >> 8, k = i & 255;
      T[i] = f2b(W[(size_t)k * 128 + n]);
    }
  }
}

// ---------------- input projection ----------------
__global__ __launch_bounds__(256) void lin_in_kernel(
    const float* __restrict__ x, const float* __restrict__ pos,
    const float* __restrict__ W, const float* __restrict__ b,
    float* __restrict__ h, int Nn) {
  int gi = blockIdx.x * 256 + threadIdx.x;
  if (gi >= Nn * 128) return;
  int n = gi >> 7, d = gi & 127;
  float acc = b[d];
#pragma unroll
  for (int j = 0; j < 11; ++j) acc = fmaf(x[(size_t)n * 11 + j], W[j * 128 + d], acc);
#pragma unroll
  for (int j = 0; j < 3; ++j) acc = fmaf(pos[(size_t)n * 3 + j], W[(11 + j) * 128 + d], acc);
  h[gi] = acc;
}

// ---------------- counting sort of edges by dst ----------------
__global__ __launch_bounds__(256) void hist_kernel(const int* __restrict__ dst, int* __restrict__ count, int Ee) {
  int i = blockIdx.x * 256 + threadIdx.x;
  if (i < Ee) atomicAdd(&count[dst[i]], 1);
}

// 3-kernel parallel exclusive scan over count[n] -> cursor[n]
__global__ __launch_bounds__(1024) void scan1_kernel(
    const int* __restrict__ count, int* __restrict__ cursor, int* __restrict__ bsum, int n) {
  __shared__ int buf[1024];
  int i = blockIdx.x * 1024 + threadIdx.x;
  int v = (i < n) ? count[i] : 0;
  buf[threadIdx.x] = v;
  __syncthreads();
  for (int off = 1; off < 1024; off <<= 1) {
    int t = (threadIdx.x >= off) ? buf[threadIdx.x - off] : 0;
    __syncthreads();
    buf[threadIdx.x] += t;
    __syncthreads();
  }
  if (i < n) cursor[i] = buf[threadIdx.x] - v;  // exclusive within block
  if (threadIdx.x == 1023) bsum[blockIdx.x] = buf[1023];
}
__global__ __launch_bounds__(1024) void scan2_kernel(int* __restrict__ bsum, int nb) {
  __shared__ int buf[1024];
  int v = (threadIdx.x < nb) ? bsum[threadIdx.x] : 0;
  buf[threadIdx.x] = v;
  __syncthreads();
  for (int off = 1; off < 1024; off <<= 1) {
    int t = (threadIdx.x >= off) ? buf[threadIdx.x - off] : 0;
    __syncthreads();
    buf[threadIdx.x] += t;
    __syncthreads();
  }
  if (threadIdx.x < nb) bsum[threadIdx.x] = buf[threadIdx.x] - v;  // exclusive
}
__global__ __launch_bounds__(1024) void scan3_kernel(
    int* __restrict__ cursor, const int* __restrict__ bsum, int n) {
  int i = blockIdx.x * 1024 + threadIdx.x;
  if (i < n) cursor[i] += bsum[blockIdx.x];
}

__global__ __launch_bounds__(256) void scatter_kernel(
    const int* __restrict__ src, const int* __restrict__ dst, const float* __restrict__ ea,
    int* __restrict__ cursor, int* __restrict__ dst_s, int* __restrict__ src_s,
    float* __restrict__ ea_s, int Ee) {
  int e = blockIdx.x * 256 + threadIdx.x;
  if (e >= Ee) return;
  int dn = dst[e];
  int pos = atomicAdd(&cursor[dn], 1);
  dst_s[pos] = dn;
  src_s[pos] = src[e];
  *(float4*)(ea_s + (size_t)pos * 4) = *(const float4*)(ea + (size_t)e * 4);
}

// per-64-edge-tile segment-start bitmask (bit i = edge 64T+i starts a run)
__global__ __launch_bounds__(256) void mask_kernel(
    const int* __restrict__ dst_s, unsigned long long* __restrict__ masks, int Ee, int nt) {
  int tile = blockIdx.x * 4 + (threadIdx.x >> 6);
  int lane = threadIdx.x & 63;
  if (tile >= nt) return;
  int e = tile * 64 + lane;
  bool start;
  if (e >= Ee || lane == 0) start = true;
  else start = (dst_s[e] != dst_s[e - 1]);
  unsigned long long m = __ballot(start);
  if (lane == 0) masks[tile] = m;
}

// ---------------- pq_kernel: P = h@W1a + b1 (folded), Q = h@W1b ----------------
// (standalone for layer 0; later layers fused into upd_kernel)
// Also zeroes this block's aggr rows for layer 0 (last memset fused away;
// race-free: one writer per row, edge launch is stream-ordered after).
__global__ __launch_bounds__(256, 4) void pq_kernel(
    const float* __restrict__ h, const unsigned short* __restrict__ W1abT,
    const float* __restrict__ b1n,
    unsigned short* __restrict__ P, unsigned short* __restrict__ Q,
    float* __restrict__ aggr, int Nn) {
  __shared__ unsigned short hs[64 * TS];
  const int tid = threadIdx.x;
  const int row0 = blockIdx.x * 64;
#pragma unroll
  for (int i = 0; i < 8; ++i) {
    int idx = tid + i * 256;
    int r = idx >> 5, c4 = (idx & 31) << 2;
    float4 v = make_float4(0.f, 0.f, 0.f, 0.f);
    if (row0 + r < Nn) {
      v = *(const float4*)(h + (size_t)(row0 + r) * 128 + c4);
      *(float4*)(aggr + (size_t)(row0 + r) * 128 + c4) = make_float4(0.f, 0.f, 0.f, 0.f);
    }
    *(uint2*)&hs[r * TS + c4] = make_uint2(pk2(v.x, v.y), pk2(v.z, v.w));
  }
  __syncthreads();
  const int lane = tid & 63, wv = tid >> 6;
  const int m16 = lane & 15, quad = lane >> 4;
  floatx4 acc[4][4];
#pragma unroll
  for (int mt = 0; mt < 4; ++mt)
#pragma unroll
    for (int nt = 0; nt < 4; ++nt) acc[mt][nt] = (floatx4)(0.0f);
  const __bf16* WT = (const __bf16*)W1abT;
  const __bf16* TlB = (const __bf16*)hs;
#pragma unroll
  for (int kb = 0; kb < 4; ++kb) {
    bf16x8 a[4], w[4];
#pragma unroll
    for (int mt = 0; mt < 4; ++mt)
      a[mt] = *(const bf16x8*)(TlB + (16 * mt + m16) * TS + kb * 32 + quad * 8);
#pragma unroll
    for (int nt = 0; nt < 4; ++nt)
      w[nt] = *(const bf16x8*)(WT + (size_t)(64 * wv + 16 * nt + m16) * 128 + kb * 32 + quad * 8);
#pragma unroll
    for (int mt = 0; mt < 4; ++mt)
#pragma unroll
      for (int nt = 0; nt < 4; ++nt)
        acc[mt][nt] = __builtin_amdgcn_mfma_f32_16x16x32_bf16(w[nt], a[mt], acc[mt][nt], 0, 0, 0);
  }
#pragma unroll
  for (int mt = 0; mt < 4; ++mt) {
    int row = row0 + 16 * mt + m16;
    if (row >= Nn) continue;
#pragma unroll
    for (int nt = 0; nt < 4; ++nt) {
      int n0 = 64 * wv + 16 * nt + 4 * quad;
      floatx4 A = acc[mt][nt];
      if (n0 < 128) {
        float4 bb = *(const float4*)(b1n + n0);
        uint2 o = make_uint2(pk2(A[0] + bb.x, A[1] + bb.y), pk2(A[2] + bb.z, A[3] + bb.w));
        *(uint2*)(P + (size_t)row * 128 + n0) = o;
      } else {
        uint2 o = make_uint2(pk2(A[0], A[1]), pk2(A[2], A[3]));
        *(uint2*)(Q + (size_t)row * 128 + (n0 - 128)) = o;
      }
    }
  }
}

// ---------------- edge kernel helpers ----------------
// Q-only prefetch: src is random -> these are the long-latency loads to hide.
static __device__ __forceinline__ void gather_q(
    const unsigned short* __restrict__ Q, const int* __restrict__ ssrcBase,
    int rw, int c0, uint4* qv) {
#pragma unroll
  for (int p = 0; p < 4; ++p) {
    int sna = ssrcBase[16 * p + rw];
    qv[p] = *(const uint4*)(Q + (size_t)sna * 128 + c0);
  }
}

// P loads inline: dst-sorted edges -> ~4 distinct dst rows per 64-edge tile,
// so these hit L1/L2. b1 is pre-folded into P (R9) -> no bias regs/adds here.
static __device__ __forceinline__ void build_T(
    unsigned short* __restrict__ TlBuf,
    const unsigned short* __restrict__ P, const uint4* qv,
    const int* __restrict__ sdstBase, const float* __restrict__ seaBase,
    const f32x2 (*__restrict__ wc2)[4], int rw, int c0) {
  uint4 pv[4];
#pragma unroll
  for (int p = 0; p < 4; ++p) {
    int dn = sdstBase[16 * p + rw];
    int dna = dn < 0 ? 0 : dn;
    pv[p] = *(const uint4*)(P + (size_t)dna * 128 + c0);
  }
#pragma unroll
  for (int p = 0; p < 4; ++p) {
    int row = 16 * p + rw;
    int dn = sdstBase[row];
    uint4 out = make_uint4(0u, 0u, 0u, 0u);
    if (dn >= 0) {
      float e0 = seaBase[row * 4 + 0], e1 = seaBase[row * 4 + 1];
      float e2 = seaBase[row * 4 + 2], e3 = seaBase[row * 4 + 3];
      unsigned pu[4] = {pv[p].x, pv[p].y, pv[p].z, pv[p].w};
      unsigned qu[4] = {qv[p].x, qv[p].y, qv[p].z, qv[p].w};
      unsigned ou[4];
#pragma unroll
      for (int g = 0; g < 4; ++g) {
        f32x2 t = up2(pu[g]) + up2(qu[g]);            // v_pk_add_f32
        t = VFMA(sp2(e0), wc2[0][g], t);              // v_pk_fma_f32
        t = VFMA(sp2(e1), wc2[1][g], t);
        t = VFMA(sp2(e2), wc2[2][g], t);
        t = VFMA(sp2(e3), wc2[3][g], t);
        t = VMAX(t, sp2(0.f));                        // v_pk_max_f32
        ou[g] = pk2(t.x, t.y);
      }
      out = make_uint4(ou[0], ou[1], ou[2], ou[3]);
    }
    *(uint4*)&TlBuf[row * TS + c0] = out;
  }
}

// W2 fragments streamed from global (L2-resident 32 KB) -> no persistent regs
static __device__ __forceinline__ void mfma_B(
    const unsigned short* __restrict__ TlBuf, const __bf16* __restrict__ WT,
    int m16, int quad, int wv, floatx4 acc[4][2]) {
#pragma unroll
  for (int mt = 0; mt < 4; ++mt) { acc[mt][0] = (floatx4)(0.0f); acc[mt][1] = (floatx4)(0.0f); }
  const __bf16* TlB = (const __bf16*)TlBuf;
#pragma unroll
  for (int kb = 0; kb < 4; ++kb) {
    bf16x8 w0 = *(const bf16x8*)(WT + (size_t)(32 * wv + m16) * 128 + kb * 32 + quad * 8);
    bf16x8 w1 = *(const bf16x8*)(WT + (size_t)(32 * wv + 16 + m16) * 128 + kb * 32 + quad * 8);
    bf16x8 a[4];
#pragma unroll
    for (int mt = 0; mt < 4; ++mt)
      a[mt] = *(const bf16x8*)(TlB + (16 * mt + m16) * TS + kb * 32 + quad * 8);
#pragma unroll
    for (int mt = 0; mt < 4; ++mt) {
      acc[mt][0] = __builtin_amdgcn_mfma_f32_16x16x32_bf16(w0, a[mt], acc[mt][0], 0, 0, 0);
      acc[mt][1] = __builtin_amdgcn_mfma_f32_16x16x32_bf16(w1, a[mt], acc[mt][1], 0, 0, 0);
    }
  }
}

static __device__ __forceinline__ void epi_m(
    unsigned short* __restrict__ TlBuf, floatx4 acc[4][2],
    const float* __restrict__ B2f, int m16, int quad, int wv) {
  int n0 = 32 * wv + 4 * quad;
  float4 b0 = *(const float4*)(B2f + n0);
  float4 b1q = *(const float4*)(B2f + n0 + 16);
  f32x2 bz0 = mk2(b0.x, b0.y), bz1 = mk2(b0.z, b0.w);
  f32x2 bz2 = mk2(b1q.x, b1q.y), bz3 = mk2(b1q.z, b1q.w);
#pragma unroll
  for (int mt = 0; mt < 4; ++mt) {
    int row = 16 * mt + m16;
    floatx4 A0 = acc[mt][0], A1 = acc[mt][1];
    f32x2 t0 = VMAX(mk2(A0[0], A0[1]) + bz0, sp2(0.f));
    f32x2 t1 = VMAX(mk2(A0[2], A0[3]) + bz1, sp2(0.f));
    f32x2 t2 = VMAX(mk2(A1[0], A1[1]) + bz2, sp2(0.f));
    f32x2 t3 = VMAX(mk2(A1[2], A1[3]) + bz3, sp2(0.f));
    *(uint2*)&TlBuf[row * TS + n0] = make_uint2(pk2(t0.x, t0.y), pk2(t1.x, t1.y));
    *(uint2*)&TlBuf[row * TS + n0 + 16] = make_uint2(pk2(t2.x, t2.y), pk2(t3.x, t3.y));
  }
}

// mask-driven segmented reduce; thread covers cols c4..c4+3 and 64+c4..64+c4+3
// -> each store across 16 consecutive lanes is a fully-covered 256-B group
// (R3 lesson: 32-B/lane stride-32 stores write-amplified 137->334 MB).
static __device__ __forceinline__ void seg_reduce(
    const unsigned short* __restrict__ TlBuf, const int* __restrict__ sdstBase,
    unsigned long long mask, float* __restrict__ aggr, int tid) {
  const int c4 = (tid & 15) << 2;
  const int st = tid >> 4;
  const int dfirst = sdstBase[0], dlast = sdstBase[63];
  for (int s = st; s < 64; s += 16) {
    if (!(mask & (1ull << s))) continue;
    int dn = sdstBase[s];
    if (dn < 0) continue;
    int end;
    if (s >= 63) end = 64;
    else {
      unsigned long long m2 = mask >> (s + 1);
      end = m2 ? (s + 1 + (int)__builtin_ctzll(m2)) : 64;
    }
    f32x2 a0 = sp2(0.f), a1 = sp2(0.f), a2 = sp2(0.f), a3 = sp2(0.f);
    for (int e = s; e < end; ++e) {
      uint2 v1 = *(const uint2*)&TlBuf[e * TS + c4];
      uint2 v2 = *(const uint2*)&TlBuf[e * TS + 64 + c4];
      a0 += up2(v1.x); a1 += up2(v1.y);
      a2 += up2(v2.x); a3 += up2(v2.y);
    }
    float* ap = aggr + (size_t)dn * 128 + c4;
    if (dn == dfirst || dn == dlast) {
      atomicAdd(ap + 0, a0.x); atomicAdd(ap + 1, a0.y);
      atomicAdd(ap + 2, a1.x); atomicAdd(ap + 3, a1.y);
      atomicAdd(ap + 64, a2.x); atomicAdd(ap + 65, a2.y);
      atomicAdd(ap + 66, a3.x); atomicAdd(ap + 67, a3.y);
    } else {
      *(float4*)ap = make_float4(a0.x, a0.y, a1.x, a1.y);
      *(float4*)(ap + 64) = make_float4(a2.x, a2.y, a3.x, a3.y);
    }
  }
}

// ---------------- edge message kernel: 1 tile/block, 4 barriers, 5 waves/SIMD ----------------
__global__ __launch_bounds__(256, 5) void edge_kernel(
    const unsigned short* __restrict__ P, const unsigned short* __restrict__ Q,
    const float* __restrict__ ea_s, const int* __restrict__ dst_s, const int* __restrict__ src_s,
    const unsigned long long* __restrict__ masks,
    const float* __restrict__ W1c,
    const unsigned short* __restrict__ W2fT, const float* __restrict__ B2f,
    float* __restrict__ aggr, int Ee, int nT) {
  __shared__ unsigned short Tl[64 * TS];   // 17.4 KB
  __shared__ float sea[64 * 4];            // 1 KB
  __shared__ int sdst[64], ssrc[64];       // 0.5 KB
  const int tid = threadIdx.x;
  // XCD swizzle: blocks round-robin over 8 XCDs; give each XCD a contiguous
  // range of edge tiles (perf heuristic only — any mapping is correct).
  int b = blockIdx.x;
  const int nB = gridDim.x;
  const int per = nB >> 3;
  if (b < (per << 3)) b = (b & 7) * per + (b >> 3);
  const int e0 = b * 64;
  const unsigned long long mask0 = masks[b];
  if (tid < 64) {
    int e = e0 + tid;
    bool ok = e < Ee;
    sdst[tid] = ok ? dst_s[e] : -1;
    ssrc[tid] = ok ? src_s[e] : 0;
  } else if (tid < 128) {
    int r = tid - 64;
    int e = e0 + r;
    float4 ev = (e < Ee) ? *(const float4*)(ea_s + (size_t)e * 4)
                         : make_float4(0.f, 0.f, 0.f, 0.f);
    *(float4*)&sea[r * 4] = ev;
  }
  const int lane = tid & 63, wv = tid >> 6;
  const int m16 = lane & 15, quad = lane >> 4;
  const int rw = tid >> 4, c0 = (tid & 15) << 3;

  // per-thread W1c slice (packed pairs); b1 is pre-folded into P
  f32x2 wc2[4][4];
#pragma unroll
  for (int r = 0; r < 4; ++r) {
    float4 u = *(const float4*)(W1c + r * 128 + c0);
    float4 v = *(const float4*)(W1c + r * 128 + c0 + 4);
    wc2[r][0] = mk2(u.x, u.y); wc2[r][1] = mk2(u.z, u.w);
    wc2[r][2] = mk2(v.x, v.y); wc2[r][3] = mk2(v.z, v.w);
  }
  const __bf16* WT = (const __bf16*)W2fT;
  __syncthreads();                                             // meta ready

  uint4 qv[4];
  gather_q(Q, ssrc, rw, c0, qv);                               // random-src gathers
  build_T(Tl, P, qv, sdst, sea, wc2, rw, c0);                  // t -> Tl
  __syncthreads();                                             // Tl ready

  floatx4 acc[4][2];
  mfma_B(Tl, WT, m16, quad, wv, acc);                          // m = t@W2f
  __syncthreads();                                             // Tl reads done

  epi_m(Tl, acc, B2f, m16, quad, wv);                          // m -> Tl (bf16)
  __syncthreads();                                             // m ready

  seg_reduce(Tl, sdst, mask0, aggr, tid);                      // -> aggr
}

// ---------------- fused update MLP (+ next-layer P'/Q + aggr re-zero) ----------------
__global__ __launch_bounds__(256, 4) void upd_kernel(
    float* __restrict__ h, float* __restrict__ aggr,
    const unsigned short* __restrict__ U1T, const float* __restrict__ ub1,
    const unsigned short* __restrict__ uW2fT, const float* __restrict__ uB2f, int Nn,
    const unsigned short* __restrict__ W1abT_next, const float* __restrict__ b1_next,
    unsigned short* __restrict__ P, unsigned short* __restrict__ Q) {
  __shared__ unsigned short as_[64 * AS];  // [h|aggr]; u1 overlay; then h_new overlay
  const int tid = threadIdx.x;
  const int row0 = blockIdx.x * 64;
#pragma unroll
  for (int i = 0; i < 8; ++i) {
    int idx = tid + i * 256;
    int r = idx >> 5, c4 = (idx & 31) << 2;
    float4 v = make_float4(0.f, 0.f, 0.f, 0.f);
    if (row0 + r < Nn) v = *(const float4*)(h + (size_t)(row0 + r) * 128 + c4);
    *(uint2*)&as_[r * AS + c4] = make_uint2(pk2(v.x, v.y), pk2(v.z, v.w));
  }
#pragma unroll
  for (int i = 0; i < 8; ++i) {
    int idx = tid + i * 256;
    int r = idx >> 5, c4 = (idx & 31) << 2;
    float4 v = make_float4(0.f, 0.f, 0.f, 0.f);
    if (row0 + r < Nn) {
      float* ap = aggr + (size_t)(row0 + r) * 128 + c4;
      v = *(const float4*)ap;
      // fused re-zero for next layer's edge pass (race-free: this block is
      // the only reader of these rows, and the next edge launch is stream-
      // ordered after this kernel). Replaces 3 of 4 51.2MB memset passes.
      if (W1abT_next) *(float4*)ap = make_float4(0.f, 0.f, 0.f, 0.f);
    }
    *(uint2*)&as_[r * AS + 128 + c4] = make_uint2(pk2(v.x, v.y), pk2(v.z, v.w));
  }
  __syncthreads();
  const int lane = tid & 63, wv = tid >> 6;
  const int m16 = lane & 15, quad = lane >> 4;
  const __bf16* asB = (const __bf16*)as_;
  unsigned short* u1s = as_;  // overlay (TS stride)
  // pass 1: u1 = relu([h|aggr]@U1 + ub1), K=256
  {
    floatx4 acc[4][2];
#pragma unroll
    for (int mt = 0; mt < 4; ++mt) { acc[mt][0] = (floatx4)(0.0f); acc[mt][1] = (floatx4)(0.0f); }
    const __bf16* WT = (const __bf16*)U1T;
#pragma unroll
    for (int kb = 0; kb < 8; ++kb) {
      bf16x8 w0 = *(const bf16x8*)(WT + (size_t)(32 * wv + m16) * 256 + kb * 32 + quad * 8);
      bf16x8 w1 = *(const bf16x8*)(WT + (size_t)(32 * wv + 16 + m16) * 256 + kb * 32 + quad * 8);
      bf16x8 a[4];
#pragma unroll
      for (int mt = 0; mt < 4; ++mt)
        a[mt] = *(const bf16x8*)(asB + (16 * mt + m16) * AS + kb * 32 + quad * 8);
#pragma unroll
      for (int mt = 0; mt < 4; ++mt) {
        acc[mt][0] = __builtin_amdgcn_mfma_f32_16x16x32_bf16(w0, a[mt], acc[mt][0], 0, 0, 0);
        acc[mt][1] = __builtin_amdgcn_mfma_f32_16x16x32_bf16(w1, a[mt], acc[mt][1], 0, 0, 0);
      }
    }
    __syncthreads();  // pass-1 reads of as_ complete -> safe to overlay u1
    int n0 = 32 * wv + 4 * quad;
    float4 bv0 = *(const float4*)(ub1 + n0);
    float4 bv1 = *(const float4*)(ub1 + n0 + 16);
#pragma unroll
    for (int mt = 0; mt < 4; ++mt) {
      int row = 16 * mt + m16;
      floatx4 A0 = acc[mt][0], A1 = acc[mt][1];
      *(uint2*)&u1s[row * TS + n0] =
          make_uint2(pk2(fmaxf(A0[0] + bv0.x, 0.f), fmaxf(A0[1] + bv0.y, 0.f)),
                     pk2(fmaxf(A0[2] + bv0.z, 0.f), fmaxf(A0[3] + bv0.w, 0.f)));
      *(uint2*)&u1s[row * TS + n0 + 16] =
          make_uint2(pk2(fmaxf(A1[0] + bv1.x, 0.f), fmaxf(A1[1] + bv1.y, 0.f)),
                     pk2(fmaxf(A1[2] + bv1.z, 0.f), fmaxf(A1[3] + bv1.w, 0.f)));
    }
  }
  __syncthreads();
  // pass 2: h_new = h + relu(u1@U2f + uB2f), K=128; write global + LDS bf16
  {
    floatx4 acc[4][2];
#pragma unroll
    for (int mt = 0; mt < 4; ++mt) { acc[mt][0] = (floatx4)(0.0f); acc[mt][1] = (floatx4)(0.0f); }
    const __bf16* WT = (const __bf16*)uW2fT;
    const __bf16* u1B = (const __bf16*)u1s;
#pragma unroll
    for (int kb = 0; kb < 4; ++kb) {
      bf16x8 w0 = *(const bf16x8*)(WT + (size_t)(32 * wv + m16) * 128 + kb * 32 + quad * 8);
      bf16x8 w1 = *(const bf16x8*)(WT + (size_t)(32 * wv + 16 + m16) * 128 + kb * 32 + quad * 8);
      bf16x8 a[4];
#pragma unroll
      for (int mt = 0; mt < 4; ++mt)
        a[mt] = *(const bf16x8*)(u1B + (16 * mt + m16) * TS + kb * 32 + quad * 8);
#pragma unroll
      for (int mt = 0; mt < 4; ++mt) {
        acc[mt][0] = __builtin_amdgcn_mfma_f32_16x16x32_bf16(w0, a[mt], acc[mt][0], 0, 0, 0);
        acc[mt][1] = __builtin_amdgcn_mfma_f32_16x16x32_bf16(w1, a[mt], acc[mt][1], 0, 0, 0);
      }
    }
    __syncthreads();  // pass-2 reads of u1s complete -> safe to overlay h_new
    int n0 = 32 * wv + 4 * quad;
    float4 bv0 = *(const float4*)(uB2f + n0);
    float4 bv1 = *(const float4*)(uB2f + n0 + 16);
#pragma unroll
    for (int mt = 0; mt < 4; ++mt) {
      int rloc = 16 * mt + m16;
      int row = row0 + rloc;
      floatx4 A0 = acc[mt][0], A1 = acc[mt][1];
      if (row < Nn) {
        float* hp0 = h + (size_t)row * 128 + n0;
        float4 hv0 = *(float4*)hp0;
        float4 o0 = make_float4(hv0.x + fmaxf(A0[0] + bv0.x, 0.f), hv0.y + fmaxf(A0[1] + bv0.y, 0.f),
                                hv0.z + fmaxf(A0[2] + bv0.z, 0.f), hv0.w + fmaxf(A0[3] + bv0.w, 0.f));
        *(float4*)hp0 = o0;
        float* hp1 = hp0 + 16;
        float4 hv1 = *(float4*)hp1;
        float4 o1 = make_float4(hv1.x + fmaxf(A1[0] + bv1.x, 0.f), hv1.y + fmaxf(A1[1] + bv1.y, 0.f),
                                hv1.z + fmaxf(A1[2] + bv1.z, 0.f), hv1.w + fmaxf(A1[3] + bv1.w, 0.f));
        *(float4*)hp1 = o1;
        if (W1abT_next) {
          *(uint2*)&u1s[rloc * TS + n0] = make_uint2(pk2(o0.x, o0.y), pk2(o0.z, o0.w));
          *(uint2*)&u1s[rloc * TS + n0 + 16] = make_uint2(pk2(o1.x, o1.y), pk2(o1.z, o1.w));
        }
      } else if (W1abT_next) {
        *(uint2*)&u1s[rloc * TS + n0] = make_uint2(0u, 0u);
        *(uint2*)&u1s[rloc * TS + n0 + 16] = make_uint2(0u, 0u);
      }
    }
  }
  // fused next-layer P'/Q from h_new tile in LDS (b1_next folded into P)
  if (W1abT_next) {
    __syncthreads();
    floatx4 pacc[4][4];
#pragma unroll
    for (int mt = 0; mt < 4; ++mt)
#pragma unroll
      for (int nt = 0; nt < 4; ++nt) pacc[mt][nt] = (floatx4)(0.0f);
    const __bf16* WT = (const __bf16*)W1abT_next;
    const __bf16* hB = (const __bf16*)u1s;
#pragma unroll
    for (int kb = 0; kb < 4; ++kb) {
      bf16x8 a[4], w[4];
#pragma unroll
      for (int mt = 0; mt < 4; ++mt)
        a[mt] = *(const bf16x8*)(hB + (16 * mt + m16) * TS + kb * 32 + quad * 8);
#pragma unroll
      for (int nt = 0; nt < 4; ++nt)
        w[nt] = *(const bf16x8*)(WT + (size_t)(64 * wv + 16 * nt + m16) * 128 + kb * 32 + quad * 8);
#pragma unroll
      for (int mt = 0; mt < 4; ++mt)
#pragma unroll
        for (int nt = 0; nt < 4; ++nt)
          pacc[mt][nt] = __builtin_amdgcn_mfma_f32_16x16x32_bf16(w[nt], a[mt], pacc[mt][nt], 0, 0, 0);
    }
#pragma unroll
    for (int mt = 0; mt < 4; ++mt) {
      int row = row0 + 16 * mt + m16;
      if (row >= Nn) continue;
#pragma unroll
      for (int nt = 0; nt < 4; ++nt) {
        int n0 = 64 * wv + 16 * nt + 4 * quad;
        floatx4 A = pacc[mt][nt];
        if (n0 < 128) {
          float4 bb = *(const float4*)(b1_next + n0);
          uint2 o = make_uint2(pk2(A[0] + bb.x, A[1] + bb.y), pk2(A[2] + bb.z, A[3] + bb.w));
          *(uint2*)(P + (size_t)row * 128 + n0) = o;
        } else {
          uint2 o = make_uint2(pk2(A[0], A[1]), pk2(A[2], A[3]));
          *(uint2*)(Q + (size_t)row * 128 + (n0 - 128)) = o;
        }
      }
    }
  }
}

// ---------------- pooling (64-node chunks: 4x shorter serial chain) ----------------
__global__ __launch_bounds__(128) void pool_sum_kernel(
    const float* __restrict__ h, const int* __restrict__ batch,
    float* __restrict__ sums, int* __restrict__ gcnt, int Nn) {
  int n0 = blockIdx.x * 64;
  if (n0 >= Nn) return;
  int nend = min(n0 + 64, Nn);
  int d = threadIdx.x;
  int gcur = batch[n0];
  float run = 0.f;
  int cnt = 0;
  for (int n = n0; n < nend; ++n) {
    int g = batch[n];
    if (g != gcur) {
      atomicAdd(&sums[(size_t)gcur * 128 + d], run);
      if (d == 0) atomicAdd(&gcnt[gcur], cnt);
      run = 0.f; cnt = 0; gcur = g;
    }
    run += h[(size_t)n * 128 + d];
    cnt += 1;
  }
  atomicAdd(&sums[(size_t)gcur * 128 + d], run);
  if (d == 0) atomicAdd(&gcnt[gcur], cnt);
}

__global__ __launch_bounds__(128) void pred_kernel(
    const float* __restrict__ sums, const int* __restrict__ gcnt,
    const float* __restrict__ pw, const float* __restrict__ pb, float* __restrict__ out) {
  __shared__ float red[2];
  int g = blockIdx.x, d = threadIdx.x;
  float c = fmaxf((float)gcnt[g], 1.f);
  float v = (sums[(size_t)g * 128 + d] / c) * pw[d];
  for (int o = 32; o > 0; o >>= 1) v += __shfl_down(v, o, 64);
  if ((d & 63) == 0) red[d >> 6] = v;
  __syncthreads();
  if (d == 0) out[g] = red[0] + red[1] + pb[0];
}

// ---------------- launch ----------------
extern "C" void kernel_launch(void* const* d_in, const int* in_sizes, int n_in,
                              void* d_out, int out_size, void* d_ws, size_t ws_size,
                              hipStream_t stream) {
  const float* x = (const float*)d_in[0];
  const float* pos = (const float*)d_in[1];
  const int* ei = (const int*)d_in[2];
  const float* ea = (const float*)d_in[3];
  const int* batch = (const int*)d_in[4];
  const float* lin_w = (const float*)d_in[5];
  const float* lin_b = (const float*)d_in[6];
  const float* mw1 = (const float*)d_in[7];
  const float* mb1 = (const float*)d_in[8];
  const float* mg = (const float*)d_in[9];
  const float* mbb = (const float*)d_in[10];
  const float* mm = (const float*)d_in[11];
  const float* mv = (const float*)d_in[12];
  const float* mw2 = (const float*)d_in[13];
  const float* mb2 = (const float*)d_in[14];
  const float* uw1 = (const float*)d_in[15];
  const float* ub1 = (const float*)d_in[16];
  const float* ug = (const float*)d_in[17];
  const float* ubb = (const float*)d_in[18];
  const float* um = (const float*)d_in[19];
  const float* uv = (const float*)d_in[20];
  const float* uw2 = (const float*)d_in[21];
  const float* ub2 = (const float*)d_in[22];
  const float* pw = (const float*)d_in[23];
  const float* pb = (const float*)d_in[24];
  float* out = (float*)d_out;

  const int Nn = in_sizes[0] / 11;
  const int Ee = in_sizes[3] / 4;
  const int* srcp = ei;        // edge_index[0] = source j
  const int* dstp = ei + Ee;   // edge_index[1] = target i

  char* wsb = (char*)d_ws;
  size_t off = 0;
  auto alloc = [&](size_t bytes) -> void* {
    void* p = wsb + off;
    off = (off + bytes + 255) & ~(size_t)255;
    return p;
  };
  float* h = (float*)alloc((size_t)Nn * 128 * 4);
  unsigned short* Pb = (unsigned short*)alloc((size_t)Nn * 128 * 2);
  unsigned short* Qb = (unsigned short*)alloc((size_t)Nn * 128 * 2);
  float* aggr = (float*)alloc((size_t)Nn * 128 * 4);
  int* dst_s = (int*)alloc((size_t)Ee * 4);
  int* src_s = (int*)alloc((size_t)Ee * 4);
  float* ea_s = (float*)alloc((size_t)Ee * 16);
  int* count = (int*)alloc((size_t)Nn * 4);
  int* cursor = (int*)alloc((size_t)Nn * 4);
  int* bsum = (int*)alloc((size_t)1024 * 4);
  const int nTiles = (Ee + 63) / 64;
  unsigned long long* masks = (unsigned long long*)alloc((size_t)nTiles * 8);
  unsigned short* mW2fT = (unsigned short*)alloc((size_t)4 * 128 * 128 * 2);
  unsigned short* uW2fT = (unsigned short*)alloc((size_t)4 * 128 * 128 * 2);
  unsigned short* W1abT = (unsigned short*)alloc((size_t)4 * 256 * 128 * 2);
  unsigned short* U1T = (unsigned short*)alloc((size_t)4 * 128 * 256 * 2);
  float* mB2f = (float*)alloc((size_t)4 * 128 * 4);
  float* uB2f = (float*)alloc((size_t)4 * 128 * 4);
  float* sums = (float*)alloc((size_t)out_size * 128 * 4);
  int* gcnt = (int*)alloc((size_t)out_size * 4);
  (void)ws_size; (void)n_in;

  fold_kernel<<<8, 128, 0, stream>>>(mw2, mb2, mg, mbb, mm, mv,
                                     uw2, ub2, ug, ubb, um, uv,
                                     mW2fT, mB2f, uW2fT, uB2f);
  transp_kernel<<<8, 256, 0, stream>>>(mw1, uw1, W1abT, U1T);
  lin_in_kernel<<<(Nn * 128 + 255) / 256, 256, 0, stream>>>(x, pos, lin_w, lin_b, h, Nn);

  hipMemsetAsync(count, 0, (size_t)Nn * 4, stream);
  hist_kernel<<<(Ee + 255) / 256, 256, 0, stream>>>(dstp, count, Ee);
  const int NB = (Nn + 1023) / 1024;
  scan1_kernel<<<NB, 1024, 0, stream>>>(count, cursor, bsum, Nn);
  scan2_kernel<<<1, 1024, 0, stream>>>(bsum, NB);
  scan3_kernel<<<NB, 1024, 0, stream>>>(cursor, bsum, Nn);
  scatter_kernel<<<(Ee + 255) / 256, 256, 0, stream>>>(srcp, dstp, ea, cursor,
                                                       dst_s, src_s, ea_s, Ee);
  mask_kernel<<<(nTiles + 3) / 4, 256, 0, stream>>>(dst_s, masks, Ee, nTiles);

  const int gN = (Nn + 63) / 64;
  // pq also zeroes layer-0 aggr rows (last big memset fused away)
  pq_kernel<<<gN, 256, 0, stream>>>(h, W1abT, mb1, Pb, Qb, aggr, Nn);
  for (int l = 0; l < 4; ++l) {                                  // upd re-zeros for l=1..3
    edge_kernel<<<nTiles, 256, 0, stream>>>(
        Pb, Qb, ea_s, dst_s, src_s, masks,
        mw1 + (size_t)l * 260 * 128 + 256 * 128,
        mW2fT + (size_t)l * 16384, mB2f + l * 128, aggr, Ee, nTiles);
    upd_kernel<<<gN, 256, 0, stream>>>(
        h, aggr, U1T + (size_t)l * 128 * 256, ub1 + l * 128,
        uW2fT + (size_t)l * 16384, uB2f + l * 128, Nn,
        (l < 3) ? (W1abT + (size_t)(l + 1) * 256 * 128) : nullptr,
        (l < 3) ? (mb1 + (size_t)(l + 1) * 128) : nullptr, Pb, Qb);
  }

  hipMemsetAsync(sums, 0, (size_t)out_size * 128 * 4, stream);
  hipMemsetAsync(gcnt, 0, (size_t)out_size * 4, stream);
  pool_sum_kernel<<<(Nn + 63) / 64, 128, 0, stream>>>(h, batch, sums, gcnt, Nn);
  pred_kernel<<<out_size, 128, 0, stream>>>(sums, gcnt, pw, pb, out);
}